// Round 13
// baseline (308.097 us; speedup 1.0000x reference)
//
#include <hip/hip_runtime.h>
#include <hip/hip_bf16.h>

#define N_NODES 100000
#define N_EDGES 800000
#define D 128
#define K2 256     // concat [mean | x] K dimension
#define MT 128     // nodes per block in fused kernel

typedef __attribute__((ext_vector_type(8))) short bf16x8;
typedef __attribute__((ext_vector_type(4))) float f32x4;

__device__ __forceinline__ unsigned short f2bf(float f) {
    union { float f; unsigned u; } c; c.f = f;
    unsigned u = c.u;
    return (unsigned short)((u + 0x7fffu + ((u >> 16) & 1u)) >> 16);
}
__device__ __forceinline__ float bflo(unsigned u) {
    union { unsigned u; float f; } c; c.u = u << 16; return c.f;
}
__device__ __forceinline__ float bfhi(unsigned u) {
    union { unsigned u; float f; } c; c.u = u & 0xffff0000u; return c.f;
}

// ================= CSR build =================

__global__ __launch_bounds__(256) void hist_kernel(
    const int* __restrict__ dst, int* __restrict__ cnt)
{
    int e = blockIdx.x * blockDim.x + threadIdx.x;
    if (e < N_EDGES) atomicAdd(&cnt[dst[e]], 1);
}

__global__ __launch_bounds__(256) void scan_reduce(
    const int* __restrict__ degi, int* __restrict__ bsum)
{
    __shared__ int sh[256];
    int t = threadIdx.x;
    int i = blockIdx.x * 256 + t;
    sh[t] = (i < N_NODES) ? degi[i] : 0;
    __syncthreads();
    for (int off = 128; off >= 1; off >>= 1) {
        if (t < off) sh[t] += sh[t + off];
        __syncthreads();
    }
    if (t == 0) bsum[blockIdx.x] = sh[0];
}

__global__ __launch_bounds__(512) void scan_bsums(
    const int* __restrict__ bsum, int* __restrict__ boff, int nb)
{
    __shared__ int sh[512];
    int t = threadIdx.x;
    int v = (t < nb) ? bsum[t] : 0;
    sh[t] = v;
    __syncthreads();
    for (int off = 1; off < 512; off <<= 1) {
        int add = (t >= off) ? sh[t - off] : 0;
        __syncthreads();
        sh[t] += add;
        __syncthreads();
    }
    if (t < nb) boff[t] = sh[t] - v;
}

__global__ __launch_bounds__(256) void scan_write(
    const int* __restrict__ degi, const int* __restrict__ boff,
    int* __restrict__ row_ptr)
{
    __shared__ int sh[256];
    int t = threadIdx.x;
    int i = blockIdx.x * 256 + t;
    int v = (i < N_NODES) ? degi[i] : 0;
    sh[t] = v;
    __syncthreads();
    for (int off = 1; off < 256; off <<= 1) {
        int add = (t >= off) ? sh[t - off] : 0;
        __syncthreads();
        sh[t] += add;
        __syncthreads();
    }
    if (i < N_NODES) row_ptr[i] = boff[blockIdx.x] + sh[t] - v;
    if (blockIdx.x == 0 && t == 0) row_ptr[N_NODES] = N_EDGES;
}

__global__ __launch_bounds__(256) void fill_kernel(
    const int* __restrict__ src, const int* __restrict__ dst,
    const int* __restrict__ row_ptr, int* __restrict__ cnt,
    int* __restrict__ esrc)
{
    int e = blockIdx.x * blockDim.x + threadIdx.x;
    if (e < N_EDGES) {
        int d = dst[e];
        int p = row_ptr[d] + atomicAdd(&cnt[d], 1);
        esrc[p] = src[e];
    }
}

// ============ weight pre-convert: Wb[layer][j][k] = bf16([Wl | Wr]) ============
__global__ __launch_bounds__(256) void wconv_kernel(
    const float* __restrict__ Wl, const float* __restrict__ Wr,
    unsigned short* __restrict__ Wb)
{
    int idx = blockIdx.x * 256 + threadIdx.x;
    if (idx >= 3 * D * K2) return;
    int layer = idx / (D * K2);
    int rem = idx % (D * K2);
    int j = rem / K2;
    int k = rem % K2;
    float v = (k < D) ? Wl[(size_t)layer * D * D + j * D + k]
                      : Wr[(size_t)layer * D * D + j * D + (k - D)];
    Wb[idx] = f2bf(v);
}

// ============ x0 fp32 -> bf16 ============
__global__ __launch_bounds__(256) void xconv_kernel(
    const float* __restrict__ x, unsigned short* __restrict__ xb)
{
    int idx = blockIdx.x * 256 + threadIdx.x;
    if (idx >= N_NODES * D / 4) return;
    float4 v = ((const float4*)x)[idx];
    ushort4 b;
    b.x = f2bf(v.x); b.y = f2bf(v.y); b.z = f2bf(v.z); b.w = f2bf(v.w);
    ((ushort4*)xb)[idx] = b;
}

// ============ gather mean: 4 nodes per wave (16 lanes x 16B = 256B row) ============
__global__ __launch_bounds__(256) void agg_kernel(
    const unsigned short* __restrict__ xb, const int* __restrict__ rp,
    const int* __restrict__ esrc, unsigned short* __restrict__ meanb)
{
    int tid = blockIdx.x * 256 + threadIdx.x;
    int node = tid >> 4;
    int lane = tid & 15;
    if (node >= N_NODES) return;
    int beg = rp[node], end = rp[node + 1];
    float a0 = 0.f, a1 = 0.f, a2 = 0.f, a3 = 0.f;
    float a4 = 0.f, a5 = 0.f, a6 = 0.f, a7 = 0.f;
    const char* xp = (const char*)xb + lane * 16;
    int i = beg;
    for (; i + 4 <= end; i += 4) {
        int s0 = esrc[i], s1 = esrc[i + 1], s2 = esrc[i + 2], s3 = esrc[i + 3];
        uint4 u0 = *(const uint4*)(xp + (size_t)s0 * 256);
        uint4 u1 = *(const uint4*)(xp + (size_t)s1 * 256);
        uint4 u2 = *(const uint4*)(xp + (size_t)s2 * 256);
        uint4 u3 = *(const uint4*)(xp + (size_t)s3 * 256);
        a0 += bflo(u0.x) + bflo(u1.x) + bflo(u2.x) + bflo(u3.x);
        a1 += bfhi(u0.x) + bfhi(u1.x) + bfhi(u2.x) + bfhi(u3.x);
        a2 += bflo(u0.y) + bflo(u1.y) + bflo(u2.y) + bflo(u3.y);
        a3 += bfhi(u0.y) + bfhi(u1.y) + bfhi(u2.y) + bfhi(u3.y);
        a4 += bflo(u0.z) + bflo(u1.z) + bflo(u2.z) + bflo(u3.z);
        a5 += bfhi(u0.z) + bfhi(u1.z) + bfhi(u2.z) + bfhi(u3.z);
        a6 += bflo(u0.w) + bflo(u1.w) + bflo(u2.w) + bflo(u3.w);
        a7 += bfhi(u0.w) + bfhi(u1.w) + bfhi(u2.w) + bfhi(u3.w);
    }
    for (; i < end; ++i) {
        uint4 u = *(const uint4*)(xp + (size_t)esrc[i] * 256);
        a0 += bflo(u.x); a1 += bfhi(u.x);
        a2 += bflo(u.y); a3 += bfhi(u.y);
        a4 += bflo(u.z); a5 += bfhi(u.z);
        a6 += bflo(u.w); a7 += bfhi(u.w);
    }
    float sc = 1.0f / fmaxf((float)(end - beg), 1.0f);
    uint4 o;
    o.x = (unsigned)f2bf(a0 * sc) | ((unsigned)f2bf(a1 * sc) << 16);
    o.y = (unsigned)f2bf(a2 * sc) | ((unsigned)f2bf(a3 * sc) << 16);
    o.z = (unsigned)f2bf(a4 * sc) | ((unsigned)f2bf(a5 * sc) << 16);
    o.w = (unsigned)f2bf(a6 * sc) | ((unsigned)f2bf(a7 * sc) << 16);
    *(uint4*)((char*)meanb + (size_t)node * 256 + lane * 16) = o;
}

// ===== fused MFMA: h = [mean|x]@Wb^T + bl; LN; ReLU; +res =====
// block = 256 threads (4 waves), MT=128 nodes.
// Wave w: rows (w>>1)*64 .. +64 (4 row-tiles), cols (w&1)*64 .. +64 (4 col-tiles).
// B register-resident (AGPRs). Both bf16 AND fp32 outputs are repacked through
// LDS into fully-coalesced dwordx4 stores (fp32 uses the full 64KB after the
// residual reads are drained). meanb may alias the output buffer.
__global__ __launch_bounds__(256, 2) void fused_mfma_kernel(
    const unsigned short* __restrict__ xb,     // [N][D] bf16 layer input (residual)
    const unsigned short* __restrict__ meanb,  // [N][D] bf16 mean
    const unsigned short* __restrict__ Wb,     // [D][K2] bf16, this layer
    const float* __restrict__ bl,
    const float* __restrict__ gamma_,
    const float* __restrict__ beta_,
    unsigned short* __restrict__ xb_out,       // bf16 out (when !last)
    float* __restrict__ out_f32,               // fp32 out (when last)
    int addResidual, int last)
{
    __shared__ unsigned short a_lds[MT * K2];   // 64 KB, XOR-swizzled
    __shared__ float st_s[2][MT], st_ss[2][MT];
    __shared__ float mu_s[MT], rs_s[MT];

    int t = threadIdx.x;
    int w = t >> 6;
    int lane = t & 63;
    int lm = lane & 15;
    int lg = lane >> 4;
    int base = blockIdx.x * MT;
    int rowBase = (w >> 1) * 64;
    int colBase = (w & 1) * 64;

    // ---- B fragments: 4 col-tiles x 8 ks (lives in AGPRs) ----
    const unsigned short* Bp = Wb + (size_t)(colBase + lm) * K2 + lg * 8;
    bf16x8 breg[4][8];
#pragma unroll
    for (int c = 0; c < 4; ++c)
#pragma unroll
        for (int ks = 0; ks < 8; ++ks)
            breg[c][ks] = *(const bf16x8*)(Bp + c * 16 * K2 + ks * 32);

    // ---- stage mean -> bytes 0..255 per row, x -> bytes 256..511, swizzled ----
#pragma unroll
    for (int it = 0; it < 8; ++it) {
        int idx = it * 256 + t;       // 0..2047
        int n = idx >> 4, c = idx & 15;
        int node = min(base + n, N_NODES - 1);
        int sw = (n & 7) << 4;
        *(int4*)((char*)a_lds + ((n * 512 + c * 16) ^ sw)) =
            *(const int4*)(meanb + (size_t)node * D + c * 8);
        *(int4*)((char*)a_lds + ((n * 512 + 256 + c * 16) ^ sw)) =
            *(const int4*)(xb + (size_t)node * D + c * 8);
    }
    __syncthreads();

    // ---- MFMA K-loop: 4 row-tiles x 4 col-tiles, pure ds_read + MFMA ----
    f32x4 acc[4][4];
#pragma unroll
    for (int rt = 0; rt < 4; ++rt)
#pragma unroll
        for (int c = 0; c < 4; ++c) acc[rt][c] = (f32x4){0.f, 0.f, 0.f, 0.f};

    int r0 = rowBase + lm;
    int lin0 = r0 * 512 + lg * 16;
    int swz = (r0 & 7) << 4;
    const char* aB = (const char*)a_lds;

#pragma unroll
    for (int ks = 0; ks < 8; ++ks) {
        bf16x8 a[4];
#pragma unroll
        for (int rt = 0; rt < 4; ++rt)
            a[rt] = *(const bf16x8*)(aB + ((lin0 + rt * 8192 + ks * 64) ^ swz));
#pragma unroll
        for (int rt = 0; rt < 4; ++rt) {
            acc[rt][0] = __builtin_amdgcn_mfma_f32_16x16x32_bf16(a[rt], breg[0][ks], acc[rt][0], 0, 0, 0);
            acc[rt][1] = __builtin_amdgcn_mfma_f32_16x16x32_bf16(a[rt], breg[1][ks], acc[rt][1], 0, 0, 0);
            acc[rt][2] = __builtin_amdgcn_mfma_f32_16x16x32_bf16(a[rt], breg[2][ks], acc[rt][2], 0, 0, 0);
            acc[rt][3] = __builtin_amdgcn_mfma_f32_16x16x32_bf16(a[rt], breg[3][ks], acc[rt][3], 0, 0, 0);
        }
    }

    // ---- bias + LN partial stats from accumulators ----
    float bw[4], gw[4], be[4];
#pragma unroll
    for (int c = 0; c < 4; ++c) {
        int col = colBase + c * 16 + lm;
        bw[c] = bl[col]; gw[c] = gamma_[col]; be[c] = beta_[col];
    }
    float s[4][4], q[4][4];
#pragma unroll
    for (int rt = 0; rt < 4; ++rt)
#pragma unroll
        for (int r = 0; r < 4; ++r) { s[rt][r] = 0.f; q[rt][r] = 0.f; }
#pragma unroll
    for (int rt = 0; rt < 4; ++rt)
#pragma unroll
        for (int c = 0; c < 4; ++c)
#pragma unroll
            for (int r = 0; r < 4; ++r) {
                float v = acc[rt][c][r] + bw[c];
                acc[rt][c][r] = v;
                s[rt][r] += v; q[rt][r] += v * v;
            }
#pragma unroll
    for (int rt = 0; rt < 4; ++rt)
#pragma unroll
        for (int r = 0; r < 4; ++r)
#pragma unroll
            for (int m = 1; m < 16; m <<= 1) {
                s[rt][r] += __shfl_xor(s[rt][r], m);
                q[rt][r] += __shfl_xor(q[rt][r], m);
            }
    if (lm == 0) {
#pragma unroll
        for (int rt = 0; rt < 4; ++rt)
#pragma unroll
            for (int r = 0; r < 4; ++r) {
                int R = rowBase + rt * 16 + lg * 4 + r;
                st_s[w & 1][R]  = s[rt][r];
                st_ss[w & 1][R] = q[rt][r];
            }
    }
    __syncthreads();
    if (t < MT) {
        float sum = st_s[0][t] + st_s[1][t];
        float sq  = st_ss[0][t] + st_ss[1][t];
        float mu = sum * (1.f / 128.f);
        float var = sq * (1.f / 128.f) - mu * mu;
        mu_s[t] = mu;
        rs_s[t] = rsqrtf(var + 1e-5f);
    }
    __syncthreads();

    if (!last) {
        // ---- normalize + relu + residual; repack bf16 into dead mean-half ----
#pragma unroll
        for (int rt = 0; rt < 4; ++rt)
#pragma unroll
            for (int r = 0; r < 4; ++r) {
                int R = rowBase + rt * 16 + lg * 4 + r;
                float mu = mu_s[R], rs = rs_s[R];
                int rsw = (R & 7) << 4;
#pragma unroll
                for (int c = 0; c < 4; ++c) {
                    int col = colBase + c * 16 + lm;
                    float v = (acc[rt][c][r] - mu) * rs * gw[c] + be[c];
                    v = fmaxf(v, 0.f);
                    if (addResidual) {
                        unsigned short xu = *(const unsigned short*)(
                            (const char*)a_lds + ((R * 512 + 256 + col * 2) ^ rsw));
                        union { unsigned u; float f; } cv; cv.u = ((unsigned)xu) << 16;
                        v += cv.f;
                    }
                    *(unsigned short*)((char*)a_lds + ((R * 512 + col * 2) ^ rsw)) = f2bf(v);
                }
            }
        __syncthreads();
        // coalesced dwordx4 stores: 32 KB block output
#pragma unroll
        for (int it = 0; it < 8; ++it) {
            int lin = it * 4096 + t * 16;
            int row = lin >> 8;
            int c = lin & 255;
            int node = base + row;
            if (node < N_NODES) {
                uint4 v = *(const uint4*)((const char*)a_lds +
                                          ((row * 512 + c) ^ ((row & 7) << 4)));
                *(uint4*)((char*)xb_out + (size_t)node * 256 + c) = v;
            }
        }
    } else {
        // ---- last layer: compute all 16 fp32 values (residual reads drain
        // before any repack write), then repack through the full 64KB LDS and
        // store fully-coalesced dwordx4 ----
        float fv[4][4][4];
#pragma unroll
        for (int rt = 0; rt < 4; ++rt)
#pragma unroll
            for (int r = 0; r < 4; ++r) {
                int R = rowBase + rt * 16 + lg * 4 + r;
                float mu = mu_s[R], rs = rs_s[R];
                int rsw = (R & 7) << 4;
#pragma unroll
                for (int c = 0; c < 4; ++c) {
                    int col = colBase + c * 16 + lm;
                    float v = (acc[rt][c][r] - mu) * rs * gw[c] + be[c];
                    v = fmaxf(v, 0.f);
                    if (addResidual) {
                        unsigned short xu = *(const unsigned short*)(
                            (const char*)a_lds + ((R * 512 + 256 + col * 2) ^ rsw));
                        union { unsigned u; float f; } cv; cv.u = ((unsigned)xu) << 16;
                        v += cv.f;
                    }
                    fv[rt][r][c] = v;
                }
            }
        __syncthreads();   // all residual reads done; a_lds now reusable
#pragma unroll
        for (int rt = 0; rt < 4; ++rt)
#pragma unroll
            for (int r = 0; r < 4; ++r) {
                int R = rowBase + rt * 16 + lg * 4 + r;
                int rsw = (R & 7) << 4;
#pragma unroll
                for (int c = 0; c < 4; ++c) {
                    int col = colBase + c * 16 + lm;
                    *(float*)((char*)a_lds + ((R * 512 + col * 4) ^ rsw)) = fv[rt][r][c];
                }
            }
        __syncthreads();
        // coalesced dwordx4 stores: 64 KB block output (128 rows x 512B fp32)
#pragma unroll
        for (int it = 0; it < 16; ++it) {
            int lin = it * 4096 + t * 16;
            int row = lin >> 9;
            int c = lin & 511;
            int node = base + row;
            if (node < N_NODES) {
                uint4 v = *(const uint4*)((const char*)a_lds +
                                          ((row * 512 + c) ^ ((row & 7) << 4)));
                *(uint4*)((char*)out_f32 + (size_t)node * 512 + c) = v;
            }
        }
    }
}

extern "C" void kernel_launch(void* const* d_in, const int* in_sizes, int n_in,
                              void* d_out, int out_size, void* d_ws, size_t ws_size,
                              hipStream_t stream) {
    const float* x0  = (const float*)d_in[0];
    const int*   ei  = (const int*)d_in[1];
    const float* Wl  = (const float*)d_in[2];
    const float* bl  = (const float*)d_in[3];
    const float* Wr  = (const float*)d_in[4];
    const float* gam = (const float*)d_in[5];
    const float* bet = (const float*)d_in[6];
    float* out = (float*)d_out;

    const int* src = ei;
    const int* dst = ei + N_EDGES;

    // ---- workspace layout ----
    int* rp   = (int*)d_ws;            // 100352 ints
    int* cnt  = rp + 100352;           // 100352 ints (dead after fill -> Wb)
    int* bsum = cnt + 100352;          // 512
    int* boff = bsum + 512;            // 512
    int* esrc = boff + 512;            // 800000
    unsigned short* xb0 = (unsigned short*)(esrc + 800000);  // N*D bf16 (25.6 MB)
    unsigned short* xb1 = xb0 + (size_t)N_NODES * D;         // N*D bf16 (25.6 MB)
    unsigned short* Wb  = (unsigned short*)cnt;              // 192 KB

    const int nbScan = (N_NODES + 255) / 256;
    const int nbEdge = (N_EDGES + 255) / 256;
    const int aggBlocks = (N_NODES * 16 + 255) / 256;       // 6250
    const int fusedBlocks = (N_NODES + MT - 1) / MT;        // 782

    // ---- CSR build ----
    hipMemsetAsync(cnt, 0, N_NODES * sizeof(int), stream);
    hist_kernel<<<nbEdge, 256, 0, stream>>>(dst, cnt);
    scan_reduce<<<nbScan, 256, 0, stream>>>(cnt, bsum);
    scan_bsums<<<1, 512, 0, stream>>>(bsum, boff, nbScan);
    scan_write<<<nbScan, 256, 0, stream>>>(cnt, boff, rp);
    hipMemsetAsync(cnt, 0, N_NODES * sizeof(int), stream);
    fill_kernel<<<nbEdge, 256, 0, stream>>>(src, dst, rp, cnt, esrc);

    // ---- weights -> bf16 (cnt dead now), x0 -> bf16 ----
    wconv_kernel<<<(3 * D * K2 + 255) / 256, 256, 0, stream>>>(Wl, Wr, Wb);
    xconv_kernel<<<(N_NODES * D / 4 + 255) / 256, 256, 0, stream>>>(x0, xb0);

    // ---- layer 0: x=xb0, mean->xb1, out->xb1 ----
    agg_kernel<<<aggBlocks, 256, 0, stream>>>(xb0, rp, esrc, xb1);
    fused_mfma_kernel<<<fusedBlocks, 256, 0, stream>>>(
        xb0, xb1, Wb, bl, gam, bet, xb1, out, 0, 0);

    // ---- layer 1: x=xb1, mean->xb0, out->xb0 ----
    agg_kernel<<<aggBlocks, 256, 0, stream>>>(xb1, rp, esrc, xb0);
    fused_mfma_kernel<<<fusedBlocks, 256, 0, stream>>>(
        xb1, xb0, Wb + D * K2, bl + D, gam + D, bet + D, xb0, out, 1, 0);

    // ---- layer 2: x=xb0, mean->xb1, out->d_out (fp32) ----
    agg_kernel<<<aggBlocks, 256, 0, stream>>>(xb0, rp, esrc, xb1);
    fused_mfma_kernel<<<fusedBlocks, 256, 0, stream>>>(
        xb0, xb1, Wb + 2 * D * K2, bl + 2 * D, gam + 2 * D, bet + 2 * D,
        xb1, out, 1, 1);
}